// Round 4
// baseline (759.523 us; speedup 1.0000x reference)
//
#include <hip/hip_runtime.h>
#include <hip/hip_bf16.h>

typedef __bf16 bf16_t;
typedef __attribute__((ext_vector_type(8))) __bf16 bf16x8;
typedef __attribute__((ext_vector_type(4))) float f32x4;

#define Bn 8
#define Hh 128
#define Ww 128
#define HW 16384

// ---- ws byte-offset layout ----
#define WP1_B   ((size_t)0)          // 25*4*4*64*8 bf16 = 409600 B
#define WP2_B   ((size_t)409600)     // 9*2*4*64*8 bf16  = 73728 B
#define WPO_B   ((size_t)483328)     // 9*2*4*32*8 bf16  = 36864 B
#define WDCN_B  ((size_t)520192)     // 576*64 f32       = 147456 B
#define BIAS_B  ((size_t)667648)     // 224 f32
#define XT_B    ((size_t)668672)     // Xt NHWC bf16 [8][16384][128] = 33554432 B (LIVE until dcn)
#define F1_B    (XT_B + 33554432)    // feat1 [8][16384][64] bf16 = 16777216 B; OO f32[8][16384][32] aliases after conv2
#define F2_B    (F1_B + 16777216)    // feat2 [8][16384][64] bf16 = 16777216 B
// total = 67,777,536 B (< 82.4 MB proven available in R1)

// ---------------- prep: swizzle weights into MFMA B-fragment order ----------------
__global__ void prep_kernel(const float* __restrict__ w1, const float* __restrict__ w2,
                            const float* __restrict__ woff, const float* __restrict__ wdcn,
                            const float* __restrict__ b1, const float* __restrict__ b2,
                            const float* __restrict__ boff, const float* __restrict__ bdcn,
                            char* __restrict__ wsb) {
    bf16_t* wp1 = (bf16_t*)(wsb + WP1_B);
    bf16_t* wp2 = (bf16_t*)(wsb + WP2_B);
    bf16_t* wpo = (bf16_t*)(wsb + WPO_B);
    float*  wd  = (float*)(wsb + WDCN_B);
    float*  bias= (float*)(wsb + BIAS_B);
    int tid = blockIdx.x * blockDim.x + threadIdx.x;
    int nt  = gridDim.x * blockDim.x;
    for (int i = tid; i < 25*4*4*64*8; i += nt) {
        int j = i & 7, q = i >> 3;
        int n = q % 64; q /= 64;
        int g = q & 3;  q >>= 2;
        int ck = q & 3; int t = q >> 2;
        int cin = ck*32 + g*8 + j;
        wp1[i] = (bf16_t)w1[(n*128 + cin)*25 + t];
    }
    for (int i = tid; i < 9*2*4*64*8; i += nt) {
        int j = i & 7, q = i >> 3;
        int n = q % 64; q /= 64;
        int g = q & 3;  q >>= 2;
        int ck = q & 1; int t = q >> 1;
        int cin = ck*32 + g*8 + j;
        wp2[i] = (bf16_t)w2[(n*64 + cin)*9 + t];
    }
    for (int i = tid; i < 9*2*4*32*8; i += nt) {
        int j = i & 7, q = i >> 3;
        int n = q & 31; q >>= 5;
        int g = q & 3;  q >>= 2;
        int ck = q & 1; int t = q >> 1;
        int cin = ck*32 + g*8 + j;
        wpo[i] = (n < 27) ? (bf16_t)woff[(n*64 + cin)*9 + t] : (bf16_t)0.f;
    }
    for (int i = tid; i < 576*64; i += nt) {
        int o = i & 63, ck = i >> 6;
        wd[i] = wdcn[o*576 + ck];
    }
    if (tid < 64) { bias[tid] = b1[tid]; bias[64+tid] = b2[tid]; bias[160+tid] = bdcn[tid]; }
    if (tid >= 64 && tid < 96) { int n = tid - 64; bias[128+n] = (n < 27) ? boff[n] : 0.f; }
}

// ---------------- NCHW f32 (Fi||Fe) -> NHWC bf16 Xt[b][p][128] ----------------
__global__ __launch_bounds__(256) void nhwc_kernel(const float* __restrict__ Fi,
                                                   const float* __restrict__ Fe,
                                                   bf16_t* __restrict__ Xt) {
    __shared__ bf16_t tile[64][136];
    const int b  = blockIdx.y;
    const int p0 = blockIdx.x * 64;
    const int px = threadIdx.x & 63;
    const int csub = threadIdx.x >> 6;
    for (int ci = 0; ci < 32; ++ci) {
        int c = csub * 32 + ci;
        const float* src = (c < 64) ? (Fi + (((size_t)(b*64 + c)) << 14))
                                    : (Fe + (((size_t)(b*64 + (c-64))) << 14));
        tile[px][c] = (bf16_t)src[p0 + px];
    }
    __syncthreads();
    const int px2 = threadIdx.x >> 2;
    const int cc  = (threadIdx.x & 3) * 32;
    bf16x8* dst = (bf16x8*)(Xt + ((size_t)(b*HW) + p0 + px2) * 128 + cc);
    const bf16x8* srcl = (const bf16x8*)(&tile[px2][cc]);
    dst[0] = srcl[0]; dst[1] = srcl[1]; dst[2] = srcl[2]; dst[3] = srcl[3];
}

// ---------------- implicit-GEMM conv via mfma_f32_16x16x32_bf16 ----------------
template <int CIN_, int KS, int WM, int WN, bool LEAKY, int COUTP, bool OUTF32, bool OFFS>
__global__ __launch_bounds__(256) void conv_mfma(const bf16_t* __restrict__ Xt,
                                                 const bf16_t* __restrict__ Wp,
                                                 const float* __restrict__ bias,
                                                 bf16_t* __restrict__ outb,
                                                 float* __restrict__ outf,
                                                 float* __restrict__ out0) {
    constexpr int PAD = KS / 2;
    constexpr int HR  = WM + KS - 1;
    constexpr int HC  = 32 + KS - 1;
    constexpr int NC  = CIN_ / 32;
    __shared__ bf16_t stg[HR * HC * 40];

    const int tid  = threadIdx.x;
    const int lane = tid & 63;
    const int wid  = tid >> 6;
    const int wm   = wid / WN;
    const int wn   = wid % WN;
    const int b    = blockIdx.z;
    const int h0   = blockIdx.y * WM;
    const int w0   = blockIdx.x * 32;
    const int l15  = lane & 15;
    const int l4   = lane >> 4;

    f32x4 acc[2][2];
#pragma unroll
    for (int i = 0; i < 2; ++i)
#pragma unroll
        for (int j = 0; j < 2; ++j)
#pragma unroll
            for (int r = 0; r < 4; ++r) acc[i][j][r] = 0.f;

    const int site = tid;
    const int srow = site / HC, scol = site % HC;
    const int gh = h0 - PAD + srow, gw = w0 - PAD + scol;
    const bool active = site < HR * HC;
    const bool inb = active && ((unsigned)gh < 128u) && ((unsigned)gw < 128u);
    const bf16_t Z0 = (bf16_t)0.f;
    const bf16x8 zv = {Z0, Z0, Z0, Z0, Z0, Z0, Z0, Z0};

    const bf16x8* wpt = (const bf16x8*)Wp;

    for (int ck = 0; ck < NC; ++ck) {
        if (active) {
            bf16x8 v0 = zv, v1 = zv, v2 = zv, v3 = zv;
            if (inb) {
                const bf16x8* gp = (const bf16x8*)(Xt + (((size_t)(b*HW) + (gh << 7) + gw)) * CIN_ + ck * 32);
                v0 = gp[0]; v1 = gp[1]; v2 = gp[2]; v3 = gp[3];
            }
            bf16x8* ldst = (bf16x8*)(&stg[site * 40]);
            ldst[0] = v0; ldst[1] = v1; ldst[2] = v2; ldst[3] = v3;
        }
        __syncthreads();
        int t = 0;
#pragma unroll
        for (int dy = 0; dy < KS; ++dy) {
#pragma unroll
            for (int dx = 0; dx < KS; ++dx, ++t) {
                bf16x8 a0 = *(const bf16x8*)(&stg[((wm + dy) * HC + (l15 + dx)) * 40 + l4 * 8]);
                bf16x8 a1 = *(const bf16x8*)(&stg[((wm + dy) * HC + (16 + l15 + dx)) * 40 + l4 * 8]);
                const bf16x8* wb = wpt + ((size_t)((t * NC + ck) * 4 + l4)) * COUTP + wn * 32 + l15;
                bf16x8 b0 = wb[0];
                bf16x8 b1 = wb[16];
                acc[0][0] = __builtin_amdgcn_mfma_f32_16x16x32_bf16(a0, b0, acc[0][0], 0, 0, 0);
                acc[0][1] = __builtin_amdgcn_mfma_f32_16x16x32_bf16(a0, b1, acc[0][1], 0, 0, 0);
                acc[1][0] = __builtin_amdgcn_mfma_f32_16x16x32_bf16(a1, b0, acc[1][0], 0, 0, 0);
                acc[1][1] = __builtin_amdgcn_mfma_f32_16x16x32_bf16(a1, b1, acc[1][1], 0, 0, 0);
            }
        }
        __syncthreads();
    }

    const int hrow = h0 + wm;
#pragma unroll
    for (int mh = 0; mh < 2; ++mh) {
#pragma unroll
        for (int nh = 0; nh < 2; ++nh) {
            const int n = wn * 32 + nh * 16 + l15;
            const float bs = bias[n];
#pragma unroll
            for (int r = 0; r < 4; ++r) {
                const int px = w0 + mh * 16 + l4 * 4 + r;
                float v = acc[mh][nh][r] + bs;
                if (LEAKY) v = (v >= 0.f) ? v : 0.1f * v;
                const size_t pbase = (size_t)(b * HW) + (hrow << 7) + px;
                if (OUTF32) outf[pbase * COUTP + n] = v;
                else        outb[pbase * COUTP + n] = (bf16_t)v;
                if (OFFS) {
                    if (n < 18) out0[(((size_t)(b * 18 + n)) << 14) + (hrow << 7) + px] = v;
                }
            }
        }
    }
}

// ---------------- copy Fi -> Ff[:, 0:64] (float4) ----------------
__global__ void copy_fi(const float* __restrict__ Fi, float* __restrict__ out1) {
    const int b = blockIdx.y;
    const int i = blockIdx.x * blockDim.x + threadIdx.x;
    const int e = i << 2;
    const int c = e >> 14;
    const int p = e & 16383;
    const float4* src = reinterpret_cast<const float4*>(Fi);
    float4* dst = reinterpret_cast<float4*>(out1);
    size_t se = ((size_t)b << 20) + e;
    size_t de = (((size_t)(b * 128 + c)) << 14) + p;
    dst[de >> 2] = src[se >> 2];
}

// ---------------- DCNv2 v2: sample Fe from NHWC bf16 Xt (ch 64..127) ----------------
__global__ __launch_bounds__(256) void dcn_kernel(const bf16_t* __restrict__ Xt,
                                                  const float* __restrict__ oo,
                                                  const float* __restrict__ wr,
                                                  const float* __restrict__ bias,
                                                  float* __restrict__ out1) {
    const int p = blockIdx.x * 256 + threadIdx.x;
    const int b = blockIdx.y;
    const int h = p >> 7;
    const int w = p & 127;

    float acc[64];
#pragma unroll
    for (int o = 0; o < 64; ++o) acc[o] = bias[o];

    const float* oob = oo + ((size_t)(b * HW) + p) * 32;
    // Fe slice of Xt: channel offset 64, per-pixel stride 128
    const bf16_t* feb = Xt + ((size_t)(b * HW)) * 128 + 64;

    for (int k = 0; k < 9; ++k) {
        const int ky = k / 3, kx = k % 3;
        const float o1v = oob[k];
        const float o2v = oob[9 + k];
        const float ml  = oob[18 + k];
        const float m = 1.f / (1.f + expf(-ml));

        const float y = (float)(h - 1 + ky) + o1v;
        const float x = (float)(w - 1 + kx) + o2v;
        const float y0f = floorf(y), x0f = floorf(x);
        const float fy = y - y0f, fx = x - x0f;
        const int y0 = (int)y0f, x0 = (int)x0f;

        const bool vy0 = (unsigned)y0 < 128u;
        const bool vy1 = (unsigned)(y0 + 1) < 128u;
        const bool vx0 = (unsigned)x0 < 128u;
        const bool vx1 = (unsigned)(x0 + 1) < 128u;

        const int y0c = min(max(y0, 0), 127);
        const int y1c = min(max(y0 + 1, 0), 127);
        const int x0c = min(max(x0, 0), 127);
        const int x1c = min(max(x0 + 1, 0), 127);

        float w00 = (1.f - fy) * (1.f - fx) * m; w00 = (vy0 && vx0) ? w00 : 0.f;
        float w01 = (1.f - fy) * fx * m;         w01 = (vy0 && vx1) ? w01 : 0.f;
        float w10 = fy * (1.f - fx) * m;         w10 = (vy1 && vx0) ? w10 : 0.f;
        float w11 = fy * fx * m;                 w11 = (vy1 && vx1) ? w11 : 0.f;

        const bf16_t* p00 = feb + ((size_t)((y0c << 7) + x0c)) * 128;
        const bf16_t* p01 = feb + ((size_t)((y0c << 7) + x1c)) * 128;
        const bf16_t* p10 = feb + ((size_t)((y1c << 7) + x0c)) * 128;
        const bf16_t* p11 = feb + ((size_t)((y1c << 7) + x1c)) * 128;

#pragma unroll
        for (int cc = 0; cc < 8; ++cc) {           // 8 chunks of 8 channels
            const bf16x8 v00 = *(const bf16x8*)(p00 + cc * 8);
            const bf16x8 v01 = *(const bf16x8*)(p01 + cc * 8);
            const bf16x8 v10 = *(const bf16x8*)(p10 + cc * 8);
            const bf16x8 v11 = *(const bf16x8*)(p11 + cc * 8);
            float s[8];
#pragma unroll
            for (int j = 0; j < 8; ++j) {
                s[j] = w00 * (float)v00[j] + w01 * (float)v01[j]
                     + w10 * (float)v10[j] + w11 * (float)v11[j];
            }
#pragma unroll
            for (int j = 0; j < 8; ++j) {
                const int c = cc * 8 + j;
                const float* wt = wr + (c * 9 + k) * 64;
#pragma unroll
                for (int o = 0; o < 64; ++o) acc[o] = fmaf(s[j], wt[o], acc[o]);
            }
        }
    }

#pragma unroll
    for (int o = 0; o < 64; ++o) {
        out1[(((size_t)(b * 128 + 64 + o)) << 14) + p] = acc[o];
    }
}

extern "C" void kernel_launch(void* const* d_in, const int* in_sizes, int n_in,
                              void* d_out, int out_size, void* d_ws, size_t ws_size,
                              hipStream_t stream) {
    const float* Fi    = (const float*)d_in[0];
    const float* Fe    = (const float*)d_in[1];
    const float* w1    = (const float*)d_in[2];
    const float* b1    = (const float*)d_in[3];
    const float* w2    = (const float*)d_in[4];
    const float* b2    = (const float*)d_in[5];
    const float* w_off = (const float*)d_in[6];
    const float* b_off = (const float*)d_in[7];
    const float* w_dcn = (const float*)d_in[8];
    const float* b_dcn = (const float*)d_in[9];

    char* wsb = (char*)d_ws;
    bf16_t* wp1   = (bf16_t*)(wsb + WP1_B);
    bf16_t* wp2   = (bf16_t*)(wsb + WP2_B);
    bf16_t* wpo   = (bf16_t*)(wsb + WPO_B);
    float*  wdcnr = (float*)(wsb + WDCN_B);
    float*  bias  = (float*)(wsb + BIAS_B);
    bf16_t* Xt    = (bf16_t*)(wsb + XT_B);
    bf16_t* feat1 = (bf16_t*)(wsb + F1_B);
    bf16_t* feat2 = (bf16_t*)(wsb + F2_B);
    float*  OO    = (float*)(wsb + F1_B);    // alias: feat1 dead after conv2

    float* out0 = (float*)d_out;                   // offset_out [8,18,128,128]
    float* out1 = out0 + (size_t)Bn * 18 * HW;     // Ff [8,128,128,128]

    prep_kernel<<<256, 256, 0, stream>>>(w1, w2, w_off, w_dcn, b1, b2, b_off, b_dcn, wsb);

    nhwc_kernel<<<dim3(256, 8), 256, 0, stream>>>(Fi, Fe, Xt);

    conv_mfma<128, 5, 2, 2, true, 64, false, false>
        <<<dim3(4, 64, 8), 256, 0, stream>>>(Xt, wp1, bias, feat1, nullptr, nullptr);

    conv_mfma<64, 3, 2, 2, true, 64, false, false>
        <<<dim3(4, 64, 8), 256, 0, stream>>>(feat1, wp2, bias + 64, feat2, nullptr, nullptr);

    conv_mfma<64, 3, 4, 1, false, 32, true, true>
        <<<dim3(4, 32, 8), 256, 0, stream>>>(feat2, wpo, bias + 128, nullptr, OO, out0);

    copy_fi<<<dim3(1024, 8), 256, 0, stream>>>(Fi, out1);

    dcn_kernel<<<dim3(64, 8), 256, 0, stream>>>(Xt, OO, wdcnr, bias + 160, out1);
}

// Round 6
// 354.722 us; speedup vs baseline: 2.1412x; 2.1412x over previous
//
#include <hip/hip_runtime.h>
#include <hip/hip_bf16.h>

typedef __bf16 bf16_t;
typedef __attribute__((ext_vector_type(8))) __bf16 bf16x8;
typedef __attribute__((ext_vector_type(4))) float f32x4;

#define Bn 8
#define Hh 128
#define Ww 128
#define HW 16384

// ---- ws byte-offset layout ----
#define WP1_B   ((size_t)0)          // 25*4*4*64*8 bf16 = 409600 B
#define WP2_B   ((size_t)409600)     // 9*2*4*64*8 bf16  = 73728 B
#define WPO_B   ((size_t)483328)     // 9*2*4*32*8 bf16  = 36864 B
#define WDCN_B  ((size_t)520192)     // dcn B-frags: 18*4*4*16*8 bf16 = 73728 B
#define BIAS_B  ((size_t)667648)     // 224 f32
#define XT_B    ((size_t)668672)     // Xt NHWC bf16 [8][16384][128] = 33554432 B (LIVE until dcn)
#define F1_B    (XT_B + 33554432)    // feat1 [8][16384][64] bf16 = 16777216 B; OO f32[8][32][16384] aliases after conv2
#define F2_B    (F1_B + 16777216)    // feat2 [8][16384][64] bf16 = 16777216 B
// total = 67,777,536 B

// ---------------- prep: swizzle weights into MFMA B-fragment order ----------------
__global__ void prep_kernel(const float* __restrict__ w1, const float* __restrict__ w2,
                            const float* __restrict__ woff, const float* __restrict__ wdcn,
                            const float* __restrict__ b1, const float* __restrict__ b2,
                            const float* __restrict__ boff, const float* __restrict__ bdcn,
                            char* __restrict__ wsb) {
    bf16_t* wp1 = (bf16_t*)(wsb + WP1_B);
    bf16_t* wp2 = (bf16_t*)(wsb + WP2_B);
    bf16_t* wpo = (bf16_t*)(wsb + WPO_B);
    bf16_t* wd  = (bf16_t*)(wsb + WDCN_B);
    float*  bias= (float*)(wsb + BIAS_B);
    int tid = blockIdx.x * blockDim.x + threadIdx.x;
    int nt  = gridDim.x * blockDim.x;
    for (int i = tid; i < 25*4*4*64*8; i += nt) {
        int j = i & 7, q = i >> 3;
        int n = q % 64; q /= 64;
        int g = q & 3;  q >>= 2;
        int ck = q & 3; int t = q >> 2;
        int cin = ck*32 + g*8 + j;
        wp1[i] = (bf16_t)w1[(n*128 + cin)*25 + t];
    }
    for (int i = tid; i < 9*2*4*64*8; i += nt) {
        int j = i & 7, q = i >> 3;
        int n = q % 64; q /= 64;
        int g = q & 3;  q >>= 2;
        int ck = q & 1; int t = q >> 1;
        int cin = ck*32 + g*8 + j;
        wp2[i] = (bf16_t)w2[(n*64 + cin)*9 + t];
    }
    for (int i = tid; i < 9*2*4*32*8; i += nt) {
        int j = i & 7, q = i >> 3;
        int n = q & 31; q >>= 5;
        int g = q & 3;  q >>= 2;
        int ck = q & 1; int t = q >> 1;
        int cin = ck*32 + g*8 + j;
        wpo[i] = (n < 27) ? (bf16_t)woff[(n*64 + cin)*9 + t] : (bf16_t)0.f;
    }
    // dcn B-frags: frag f = ((kc*4 + ntile)*4 + l4)*16 + l15 ; element j:
    //   k_global = kc*32 + l4*8 + j ; tap = k_global>>6 ; c = k_global&63 ; n = ntile*16+l15
    for (int i = tid; i < 18*4*4*16*8; i += nt) {
        int j = i & 7, f = i >> 3;
        int l15 = f & 15; f >>= 4;
        int l4  = f & 3;  f >>= 2;
        int ntl = f & 3;  int kc = f >> 2;
        int kg = kc*32 + l4*8 + j;
        int tap = kg >> 6, c = kg & 63;
        int n = ntl*16 + l15;
        wd[i] = (bf16_t)wdcn[n*576 + c*9 + tap];
    }
    if (tid < 64) { bias[tid] = b1[tid]; bias[64+tid] = b2[tid]; bias[160+tid] = bdcn[tid]; }
    if (tid >= 64 && tid < 96) { int n = tid - 64; bias[128+n] = (n < 27) ? boff[n] : 0.f; }
}

// ---------------- NCHW f32 (Fi||Fe) -> NHWC bf16 Xt[b][p][128] ----------------
__global__ __launch_bounds__(256) void nhwc_kernel(const float* __restrict__ Fi,
                                                   const float* __restrict__ Fe,
                                                   bf16_t* __restrict__ Xt) {
    __shared__ bf16_t tile[64][136];
    const int b  = blockIdx.y;
    const int p0 = blockIdx.x * 64;
    const int px = threadIdx.x & 63;
    const int csub = threadIdx.x >> 6;
    for (int ci = 0; ci < 32; ++ci) {
        int c = csub * 32 + ci;
        const float* src = (c < 64) ? (Fi + (((size_t)(b*64 + c)) << 14))
                                    : (Fe + (((size_t)(b*64 + (c-64))) << 14));
        tile[px][c] = (bf16_t)src[p0 + px];
    }
    __syncthreads();
    const int px2 = threadIdx.x >> 2;
    const int cc  = (threadIdx.x & 3) * 32;
    bf16x8* dst = (bf16x8*)(Xt + ((size_t)(b*HW) + p0 + px2) * 128 + cc);
    const bf16x8* srcl = (const bf16x8*)(&tile[px2][cc]);
    dst[0] = srcl[0]; dst[1] = srcl[1]; dst[2] = srcl[2]; dst[3] = srcl[3];
}

// ---------------- implicit-GEMM conv via mfma_f32_16x16x32_bf16 ----------------
// OUTF32 path writes NCHW f32 (stride HW, COUTP channels).
template <int CIN_, int KS, int WM, int WN, bool LEAKY, int COUTP, bool OUTF32, bool OFFS>
__global__ __launch_bounds__(256) void conv_mfma(const bf16_t* __restrict__ Xt,
                                                 const bf16_t* __restrict__ Wp,
                                                 const float* __restrict__ bias,
                                                 bf16_t* __restrict__ outb,
                                                 float* __restrict__ outf,
                                                 float* __restrict__ out0) {
    constexpr int PAD = KS / 2;
    constexpr int HR  = WM + KS - 1;
    constexpr int HC  = 32 + KS - 1;
    constexpr int NC  = CIN_ / 32;
    __shared__ bf16_t stg[HR * HC * 40];

    const int tid  = threadIdx.x;
    const int lane = tid & 63;
    const int wid  = tid >> 6;
    const int wm   = wid / WN;
    const int wn   = wid % WN;
    const int b    = blockIdx.z;
    const int h0   = blockIdx.y * WM;
    const int w0   = blockIdx.x * 32;
    const int l15  = lane & 15;
    const int l4   = lane >> 4;

    f32x4 acc[2][2];
#pragma unroll
    for (int i = 0; i < 2; ++i)
#pragma unroll
        for (int j = 0; j < 2; ++j)
#pragma unroll
            for (int r = 0; r < 4; ++r) acc[i][j][r] = 0.f;

    const int site = tid;
    const int srow = site / HC, scol = site % HC;
    const int gh = h0 - PAD + srow, gw = w0 - PAD + scol;
    const bool active = site < HR * HC;
    const bool inb = active && ((unsigned)gh < 128u) && ((unsigned)gw < 128u);
    const bf16_t Z0 = (bf16_t)0.f;
    const bf16x8 zv = {Z0, Z0, Z0, Z0, Z0, Z0, Z0, Z0};

    const bf16x8* wpt = (const bf16x8*)Wp;

    for (int ck = 0; ck < NC; ++ck) {
        if (active) {
            bf16x8 v0 = zv, v1 = zv, v2 = zv, v3 = zv;
            if (inb) {
                const bf16x8* gp = (const bf16x8*)(Xt + (((size_t)(b*HW) + (gh << 7) + gw)) * CIN_ + ck * 32);
                v0 = gp[0]; v1 = gp[1]; v2 = gp[2]; v3 = gp[3];
            }
            bf16x8* ldst = (bf16x8*)(&stg[site * 40]);
            ldst[0] = v0; ldst[1] = v1; ldst[2] = v2; ldst[3] = v3;
        }
        __syncthreads();
        int t = 0;
#pragma unroll
        for (int dy = 0; dy < KS; ++dy) {
#pragma unroll
            for (int dx = 0; dx < KS; ++dx, ++t) {
                bf16x8 a0 = *(const bf16x8*)(&stg[((wm + dy) * HC + (l15 + dx)) * 40 + l4 * 8]);
                bf16x8 a1 = *(const bf16x8*)(&stg[((wm + dy) * HC + (16 + l15 + dx)) * 40 + l4 * 8]);
                const bf16x8* wb = wpt + ((size_t)((t * NC + ck) * 4 + l4)) * COUTP + wn * 32 + l15;
                bf16x8 b0 = wb[0];
                bf16x8 b1 = wb[16];
                acc[0][0] = __builtin_amdgcn_mfma_f32_16x16x32_bf16(a0, b0, acc[0][0], 0, 0, 0);
                acc[0][1] = __builtin_amdgcn_mfma_f32_16x16x32_bf16(a0, b1, acc[0][1], 0, 0, 0);
                acc[1][0] = __builtin_amdgcn_mfma_f32_16x16x32_bf16(a1, b0, acc[1][0], 0, 0, 0);
                acc[1][1] = __builtin_amdgcn_mfma_f32_16x16x32_bf16(a1, b1, acc[1][1], 0, 0, 0);
            }
        }
        __syncthreads();
    }

    const int hrow = h0 + wm;
#pragma unroll
    for (int mh = 0; mh < 2; ++mh) {
#pragma unroll
        for (int nh = 0; nh < 2; ++nh) {
            const int n = wn * 32 + nh * 16 + l15;
            const float bs = bias[n];
#pragma unroll
            for (int r = 0; r < 4; ++r) {
                const int px = w0 + mh * 16 + l4 * 4 + r;
                float v = acc[mh][nh][r] + bs;
                if (LEAKY) v = (v >= 0.f) ? v : 0.1f * v;
                const size_t pix = (size_t)(hrow << 7) + px;
                if (OUTF32) outf[(((size_t)(b * COUTP + n)) << 14) + pix] = v;   // NCHW
                else        outb[(((size_t)(b * HW)) + pix) * COUTP + n] = (bf16_t)v;  // NHWC
                if (OFFS) {
                    if (n < 18) out0[(((size_t)(b * 18 + n)) << 14) + pix] = v;
                }
            }
        }
    }
}

// ---------------- copy Fi -> Ff[:, 0:64] (float4) ----------------
__global__ void copy_fi(const float* __restrict__ Fi, float* __restrict__ out1) {
    const int b = blockIdx.y;
    const int i = blockIdx.x * blockDim.x + threadIdx.x;
    const int e = i << 2;
    const int c = e >> 14;
    const int p = e & 16383;
    const float4* src = reinterpret_cast<const float4*>(Fi);
    float4* dst = reinterpret_cast<float4*>(out1);
    size_t se = ((size_t)b << 20) + e;
    size_t de = (((size_t)(b * 128 + c)) << 14) + p;
    dst[de >> 2] = src[se >> 2];
}

// ---------------- DCNv2 via MFMA ----------------
// Block: 8 waves x 32 px = 256 px. Wave tile: 32 px (2 A-groups of 16) x 64 cout.
// K = tap*64 + c (576). A-frag built in-register from bilinear sampling of Xt (NHWC, Fe=ch 64..127).
// B (w_dcn frags) staged in LDS in 2 phases: taps 0..4 (chunks 0..9, 40KB), taps 5..8 (chunks 10..17, 32KB).
__global__ __launch_bounds__(512) void dcn_mfma(const bf16_t* __restrict__ Xt,
                                                const float* __restrict__ OO,
                                                const bf16_t* __restrict__ Wd,
                                                const float* __restrict__ bias,
                                                float* __restrict__ out1) {
    __shared__ bf16_t Bs[10 * 4 * 4 * 16 * 8];   // 40960 B max phase

    const int tid  = threadIdx.x;
    const int lane = tid & 63;
    const int wave = tid >> 6;         // 0..7
    const int l15  = lane & 15;
    const int l4   = lane >> 4;        // 0..3
    const int b    = blockIdx.y;
    const int p0   = blockIdx.x * 256 + wave * 32;

    f32x4 acc[2][4];
#pragma unroll
    for (int nt = 0; nt < 4; ++nt) {
        const float bs = bias[nt * 16 + l15];
#pragma unroll
        for (int a = 0; a < 2; ++a) { acc[a][nt][0] = bs; acc[a][nt][1] = bs; acc[a][nt][2] = bs; acc[a][nt][3] = bs; }
    }

    const bf16_t* feb = Xt + ((size_t)(b * HW)) * 128 + 64;
    const bf16x8* Bsv = (const bf16x8*)Bs;
    const bf16x8* Wdv = (const bf16x8*)Wd;

#pragma unroll
    for (int phase = 0; phase < 2; ++phase) {
        // stage B frags for this phase
        const int fbase = phase * 2560;              // frag offset (chunks 0..9 | 10..17)
        const int fcnt  = phase ? 2048 : 2560;
        bf16x8* Bsw = (bf16x8*)Bs;
        for (int f = tid; f < fcnt; f += 512) Bsw[f] = Wdv[fbase + f];
        __syncthreads();

        const int t0 = phase ? 5 : 0;
        const int t1 = phase ? 9 : 5;
        for (int k = t0; k < t1; ++k) {
            const int ky = k / 3, kx = k % 3;
#pragma unroll
            for (int a = 0; a < 2; ++a) {
                const int p  = p0 + a * 16 + l15;
                const int h  = p >> 7, w = p & 127;
                const float o1v = OO[(((size_t)(b * 32 + k)) << 14) + p];
                const float o2v = OO[(((size_t)(b * 32 + 9 + k)) << 14) + p];
                const float ml  = OO[(((size_t)(b * 32 + 18 + k)) << 14) + p];
                const float m = 1.f / (1.f + __expf(-ml));

                const float y = (float)(h - 1 + ky) + o1v;
                const float x = (float)(w - 1 + kx) + o2v;
                const float y0f = floorf(y), x0f = floorf(x);
                const float fy = y - y0f, fx = x - x0f;
                const int y0 = (int)y0f, x0 = (int)x0f;

                const bool vy0 = (unsigned)y0 < 128u;
                const bool vy1 = (unsigned)(y0 + 1) < 128u;
                const bool vx0 = (unsigned)x0 < 128u;
                const bool vx1 = (unsigned)(x0 + 1) < 128u;

                const int y0c = min(max(y0, 0), 127);
                const int y1c = min(max(y0 + 1, 0), 127);
                const int x0c = min(max(x0, 0), 127);
                const int x1c = min(max(x0 + 1, 0), 127);

                float w00 = (1.f - fy) * (1.f - fx) * m; w00 = (vy0 && vx0) ? w00 : 0.f;
                float w01 = (1.f - fy) * fx * m;         w01 = (vy0 && vx1) ? w01 : 0.f;
                float w10 = fy * (1.f - fx) * m;         w10 = (vy1 && vx0) ? w10 : 0.f;
                float w11 = fy * fx * m;                 w11 = (vy1 && vx1) ? w11 : 0.f;

                const bf16_t* p00 = feb + ((size_t)((y0c << 7) + x0c)) * 128;
                const bf16_t* p01 = feb + ((size_t)((y0c << 7) + x1c)) * 128;
                const bf16_t* p10 = feb + ((size_t)((y1c << 7) + x0c)) * 128;
                const bf16_t* p11 = feb + ((size_t)((y1c << 7) + x1c)) * 128;

#pragma unroll
                for (int cc = 0; cc < 2; ++cc) {
                    const int c0 = cc * 32 + l4 * 8;
                    const bf16x8 v00 = *(const bf16x8*)(p00 + c0);
                    const bf16x8 v01 = *(const bf16x8*)(p01 + c0);
                    const bf16x8 v10 = *(const bf16x8*)(p10 + c0);
                    const bf16x8 v11 = *(const bf16x8*)(p11 + c0);
                    bf16x8 af;
#pragma unroll
                    for (int j = 0; j < 8; ++j) {
                        af[j] = (bf16_t)(w00 * (float)v00[j] + w01 * (float)v01[j]
                                       + w10 * (float)v10[j] + w11 * (float)v11[j]);
                    }
                    const int kcl = (k * 2 + cc) - phase * 10;   // chunk index within LDS
#pragma unroll
                    for (int nt = 0; nt < 4; ++nt) {
                        const bf16x8 bf = Bsv[((kcl * 4 + nt) * 4 + l4) * 16 + l15];
                        acc[a][nt] = __builtin_amdgcn_mfma_f32_16x16x32_bf16(af, bf, acc[a][nt], 0, 0, 0);
                    }
                }
            }
        }
        __syncthreads();
    }

    // epilogue: C/D 16x16: col(cout) = l15, row(px) = l4*4 + r
#pragma unroll
    for (int a = 0; a < 2; ++a) {
#pragma unroll
        for (int nt = 0; nt < 4; ++nt) {
            const int o = nt * 16 + l15;
#pragma unroll
            for (int r = 0; r < 4; ++r) {
                const int p = p0 + a * 16 + l4 * 4 + r;
                out1[(((size_t)(b * 128 + 64 + o)) << 14) + p] = acc[a][nt][r];
            }
        }
    }
}

extern "C" void kernel_launch(void* const* d_in, const int* in_sizes, int n_in,
                              void* d_out, int out_size, void* d_ws, size_t ws_size,
                              hipStream_t stream) {
    const float* Fi    = (const float*)d_in[0];
    const float* Fe    = (const float*)d_in[1];
    const float* w1    = (const float*)d_in[2];
    const float* b1    = (const float*)d_in[3];
    const float* w2    = (const float*)d_in[4];
    const float* b2    = (const float*)d_in[5];
    const float* w_off = (const float*)d_in[6];
    const float* b_off = (const float*)d_in[7];
    const float* w_dcn = (const float*)d_in[8];
    const float* b_dcn = (const float*)d_in[9];

    char* wsb = (char*)d_ws;
    bf16_t* wp1   = (bf16_t*)(wsb + WP1_B);
    bf16_t* wp2   = (bf16_t*)(wsb + WP2_B);
    bf16_t* wpo   = (bf16_t*)(wsb + WPO_B);
    bf16_t* wdcnf = (bf16_t*)(wsb + WDCN_B);
    float*  bias  = (float*)(wsb + BIAS_B);
    bf16_t* Xt    = (bf16_t*)(wsb + XT_B);
    bf16_t* feat1 = (bf16_t*)(wsb + F1_B);
    bf16_t* feat2 = (bf16_t*)(wsb + F2_B);
    float*  OO    = (float*)(wsb + F1_B);    // NCHW [b][32][HW]; alias: feat1 dead after conv2

    float* out0 = (float*)d_out;                   // offset_out [8,18,128,128]
    float* out1 = out0 + (size_t)Bn * 18 * HW;     // Ff [8,128,128,128]

    prep_kernel<<<256, 256, 0, stream>>>(w1, w2, w_off, w_dcn, b1, b2, b_off, b_dcn, wsb);

    nhwc_kernel<<<dim3(256, 8), 256, 0, stream>>>(Fi, Fe, Xt);

    conv_mfma<128, 5, 2, 2, true, 64, false, false>
        <<<dim3(4, 64, 8), 256, 0, stream>>>(Xt, wp1, bias, feat1, nullptr, nullptr);

    conv_mfma<64, 3, 2, 2, true, 64, false, false>
        <<<dim3(4, 64, 8), 256, 0, stream>>>(feat1, wp2, bias + 64, feat2, nullptr, nullptr);

    conv_mfma<64, 3, 4, 1, false, 32, true, true>
        <<<dim3(4, 32, 8), 256, 0, stream>>>(feat2, wpo, bias + 128, nullptr, OO, out0);

    copy_fi<<<dim3(1024, 8), 256, 0, stream>>>(Fi, out1);

    dcn_mfma<<<dim3(64, 8), 512, 0, stream>>>(Xt, OO, wdcnf, bias + 160, out1);
}

// Round 7
// 329.076 us; speedup vs baseline: 2.3080x; 1.0779x over previous
//
#include <hip/hip_runtime.h>
#include <hip/hip_bf16.h>

typedef __bf16 bf16_t;
typedef __attribute__((ext_vector_type(8))) __bf16 bf16x8;
typedef __attribute__((ext_vector_type(4))) float f32x4;

#define Bn 8
#define Hh 128
#define Ww 128
#define HW 16384

// ---- ws byte-offset layout ----
#define WP1_B   ((size_t)0)          // 25*4*4*64*8 bf16 = 409600 B
#define WP2_B   ((size_t)409600)     // 9*2*4*64*8 bf16  = 73728 B
#define WPO_B   ((size_t)483328)     // 9*2*4*32*8 bf16  = 36864 B
#define WDCN_B  ((size_t)520192)     // dcn B-frags: 18*4*4*16*8 bf16 = 73728 B
#define BIAS_B  ((size_t)667648)     // 224 f32
#define XT_B    ((size_t)668672)     // Xt NHWC bf16 [8][16384][128] = 33554432 B (LIVE until dcn)
#define F1_B    (XT_B + 33554432)    // feat1 [8][16384][64] bf16; OO f32[8][32][16384] aliases after conv2
#define F2_B    (F1_B + 16777216)    // feat2 [8][16384][64] bf16
// total = 67,777,536 B

// ---------------- prep: swizzle weights into MFMA B-fragment order ----------------
__global__ void prep_kernel(const float* __restrict__ w1, const float* __restrict__ w2,
                            const float* __restrict__ woff, const float* __restrict__ wdcn,
                            const float* __restrict__ b1, const float* __restrict__ b2,
                            const float* __restrict__ boff, const float* __restrict__ bdcn,
                            char* __restrict__ wsb) {
    bf16_t* wp1 = (bf16_t*)(wsb + WP1_B);
    bf16_t* wp2 = (bf16_t*)(wsb + WP2_B);
    bf16_t* wpo = (bf16_t*)(wsb + WPO_B);
    bf16_t* wd  = (bf16_t*)(wsb + WDCN_B);
    float*  bias= (float*)(wsb + BIAS_B);
    int tid = blockIdx.x * blockDim.x + threadIdx.x;
    int nt  = gridDim.x * blockDim.x;
    for (int i = tid; i < 25*4*4*64*8; i += nt) {
        int j = i & 7, q = i >> 3;
        int n = q % 64; q /= 64;
        int g = q & 3;  q >>= 2;
        int ck = q & 3; int t = q >> 2;
        int cin = ck*32 + g*8 + j;
        wp1[i] = (bf16_t)w1[(n*128 + cin)*25 + t];
    }
    for (int i = tid; i < 9*2*4*64*8; i += nt) {
        int j = i & 7, q = i >> 3;
        int n = q % 64; q /= 64;
        int g = q & 3;  q >>= 2;
        int ck = q & 1; int t = q >> 1;
        int cin = ck*32 + g*8 + j;
        wp2[i] = (bf16_t)w2[(n*64 + cin)*9 + t];
    }
    for (int i = tid; i < 9*2*4*32*8; i += nt) {
        int j = i & 7, q = i >> 3;
        int n = q & 31; q >>= 5;
        int g = q & 3;  q >>= 2;
        int ck = q & 1; int t = q >> 1;
        int cin = ck*32 + g*8 + j;
        wpo[i] = (n < 27) ? (bf16_t)woff[(n*64 + cin)*9 + t] : (bf16_t)0.f;
    }
    for (int i = tid; i < 18*4*4*16*8; i += nt) {
        int j = i & 7, f = i >> 3;
        int l15 = f & 15; f >>= 4;
        int l4  = f & 3;  f >>= 2;
        int ntl = f & 3;  int kc = f >> 2;
        int kg = kc*32 + l4*8 + j;
        int tap = kg >> 6, c = kg & 63;
        int n = ntl*16 + l15;
        wd[i] = (bf16_t)wdcn[n*576 + c*9 + tap];
    }
    if (tid < 64) { bias[tid] = b1[tid]; bias[64+tid] = b2[tid]; bias[160+tid] = bdcn[tid]; }
    if (tid >= 64 && tid < 96) { int n = tid - 64; bias[128+n] = (n < 27) ? boff[n] : 0.f; }
}

// ---------------- NCHW f32 (Fi||Fe) -> NHWC bf16 Xt[b][p][128] ----------------
__global__ __launch_bounds__(256) void nhwc_kernel(const float* __restrict__ Fi,
                                                   const float* __restrict__ Fe,
                                                   bf16_t* __restrict__ Xt) {
    __shared__ bf16_t tile[64][136];
    const int b  = blockIdx.y;
    const int p0 = blockIdx.x * 64;
    const int px = threadIdx.x & 63;
    const int csub = threadIdx.x >> 6;
    for (int ci = 0; ci < 32; ++ci) {
        int c = csub * 32 + ci;
        const float* src = (c < 64) ? (Fi + (((size_t)(b*64 + c)) << 14))
                                    : (Fe + (((size_t)(b*64 + (c-64))) << 14));
        tile[px][c] = (bf16_t)src[p0 + px];
    }
    __syncthreads();
    const int px2 = threadIdx.x >> 2;
    const int cc  = (threadIdx.x & 3) * 32;
    bf16x8* dst = (bf16x8*)(Xt + ((size_t)(b*HW) + p0 + px2) * 128 + cc);
    const bf16x8* srcl = (const bf16x8*)(&tile[px2][cc]);
    dst[0] = srcl[0]; dst[1] = srcl[1]; dst[2] = srcl[2]; dst[3] = srcl[3];
}

// ---------------- implicit-GEMM conv, wave tile 64px x 64co ----------------
// Block: 4 waves, wave w = output row (h0+w), px w0..w0+63, all COUTP couts.
// acc[4][NT] f32x4: m = px quarter (16 px), nt = cout 16-tile.
// LDS halo: [HR rows][HC cols][32ch] per K-chunk, ch-stride padded to 40 elems (80 B).
template <int CIN_, int KS, int COUTP, bool LEAKY, bool OUTF32, bool OFFS>
__global__ __launch_bounds__(256) void conv_mfma(const bf16_t* __restrict__ Xt,
                                                 const bf16_t* __restrict__ Wp,
                                                 const float* __restrict__ bias,
                                                 bf16_t* __restrict__ outb,
                                                 float* __restrict__ outf,
                                                 float* __restrict__ out0) {
    constexpr int PAD = KS / 2;
    constexpr int HR  = 4 + KS - 1;        // 8 (KS=5) / 6 (KS=3)
    constexpr int HC  = 64 + KS - 1;       // 68 / 66
    constexpr int NC  = CIN_ / 32;
    constexpr int NT  = COUTP / 16;        // cout 16-tiles per wave
    __shared__ bf16_t stg[HR * HC * 40];   // 43.5 KB / 31.7 KB

    const int tid  = threadIdx.x;
    const int lane = tid & 63;
    const int wid  = tid >> 6;             // wave = output row within block
    const int b    = blockIdx.z;
    const int h0   = blockIdx.y * 4;
    const int w0   = blockIdx.x * 64;
    const int l15  = lane & 15;
    const int l4   = lane >> 4;

    f32x4 acc[4][NT];
#pragma unroll
    for (int m = 0; m < 4; ++m)
#pragma unroll
        for (int nt = 0; nt < NT; ++nt)
#pragma unroll
            for (int r = 0; r < 4; ++r) acc[m][nt][r] = 0.f;

    const bf16_t Z0 = (bf16_t)0.f;
    const bf16x8 zv = {Z0, Z0, Z0, Z0, Z0, Z0, Z0, Z0};
    const bf16x8* wpt = (const bf16x8*)Wp;

    for (int ck = 0; ck < NC; ++ck) {
        for (int s = tid; s < HR * HC; s += 256) {
            const int srow = s / HC, scol = s % HC;
            const int gh = h0 - PAD + srow, gw = w0 - PAD + scol;
            bf16x8 v0 = zv, v1 = zv, v2 = zv, v3 = zv;
            if (((unsigned)gh < 128u) && ((unsigned)gw < 128u)) {
                const bf16x8* gp = (const bf16x8*)(Xt + (((size_t)(b*HW) + (gh << 7) + gw)) * CIN_ + ck * 32);
                v0 = gp[0]; v1 = gp[1]; v2 = gp[2]; v3 = gp[3];
            }
            bf16x8* ldst = (bf16x8*)(&stg[s * 40]);
            ldst[0] = v0; ldst[1] = v1; ldst[2] = v2; ldst[3] = v3;
        }
        __syncthreads();
        int t = 0;
#pragma unroll
        for (int dy = 0; dy < KS; ++dy) {
#pragma unroll
            for (int dx = 0; dx < KS; ++dx, ++t) {
                bf16x8 a[4];
#pragma unroll
                for (int m = 0; m < 4; ++m)
                    a[m] = *(const bf16x8*)(&stg[((wid + dy) * HC + (m * 16 + l15 + dx)) * 40 + l4 * 8]);
                bf16x8 bb[NT];
#pragma unroll
                for (int nt = 0; nt < NT; ++nt)
                    bb[nt] = wpt[((size_t)((t * NC + ck) * 4 + l4)) * COUTP + nt * 16 + l15];
#pragma unroll
                for (int m = 0; m < 4; ++m)
#pragma unroll
                    for (int nt = 0; nt < NT; ++nt)
                        acc[m][nt] = __builtin_amdgcn_mfma_f32_16x16x32_bf16(a[m], bb[nt], acc[m][nt], 0, 0, 0);
            }
        }
        __syncthreads();
    }

    // epilogue: C/D 16x16: col(cout) = l15, row(px) = l4*4 + r
    const int hrow = h0 + wid;
#pragma unroll
    for (int m = 0; m < 4; ++m) {
#pragma unroll
        for (int nt = 0; nt < NT; ++nt) {
            const int n = nt * 16 + l15;
            const float bs = bias[n];
#pragma unroll
            for (int r = 0; r < 4; ++r) {
                const int px = w0 + m * 16 + l4 * 4 + r;
                float v = acc[m][nt][r] + bs;
                if (LEAKY) v = (v >= 0.f) ? v : 0.1f * v;
                const size_t pix = (size_t)(hrow << 7) + px;
                if (OUTF32) outf[(((size_t)(b * COUTP + n)) << 14) + pix] = v;         // NCHW f32
                else        outb[(((size_t)(b * HW)) + pix) * COUTP + n] = (bf16_t)v;  // NHWC bf16
                if (OFFS) {
                    if (n < 18) out0[(((size_t)(b * 18 + n)) << 14) + pix] = v;
                }
            }
        }
    }
}

// ---------------- copy Fi -> Ff[:, 0:64] (float4) ----------------
__global__ void copy_fi(const float* __restrict__ Fi, float* __restrict__ out1) {
    const int b = blockIdx.y;
    const int i = blockIdx.x * blockDim.x + threadIdx.x;
    const int e = i << 2;
    const int c = e >> 14;
    const int p = e & 16383;
    const float4* src = reinterpret_cast<const float4*>(Fi);
    float4* dst = reinterpret_cast<float4*>(out1);
    size_t se = ((size_t)b << 20) + e;
    size_t de = (((size_t)(b * 128 + c)) << 14) + p;
    dst[de >> 2] = src[se >> 2];
}

// ---------------- DCNv2 via MFMA ----------------
__global__ __launch_bounds__(512) void dcn_mfma(const bf16_t* __restrict__ Xt,
                                                const float* __restrict__ OO,
                                                const bf16_t* __restrict__ Wd,
                                                const float* __restrict__ bias,
                                                float* __restrict__ out1) {
    __shared__ bf16_t Bs[10 * 4 * 4 * 16 * 8];

    const int tid  = threadIdx.x;
    const int lane = tid & 63;
    const int wave = tid >> 6;
    const int l15  = lane & 15;
    const int l4   = lane >> 4;
    const int b    = blockIdx.y;
    const int p0   = blockIdx.x * 256 + wave * 32;

    f32x4 acc[2][4];
#pragma unroll
    for (int nt = 0; nt < 4; ++nt) {
        const float bs = bias[nt * 16 + l15];
#pragma unroll
        for (int a = 0; a < 2; ++a) { acc[a][nt][0] = bs; acc[a][nt][1] = bs; acc[a][nt][2] = bs; acc[a][nt][3] = bs; }
    }

    const bf16_t* feb = Xt + ((size_t)(b * HW)) * 128 + 64;
    const bf16x8* Bsv = (const bf16x8*)Bs;
    const bf16x8* Wdv = (const bf16x8*)Wd;

#pragma unroll
    for (int phase = 0; phase < 2; ++phase) {
        const int fbase = phase * 2560;
        const int fcnt  = phase ? 2048 : 2560;
        bf16x8* Bsw = (bf16x8*)Bs;
        for (int f = tid; f < fcnt; f += 512) Bsw[f] = Wdv[fbase + f];
        __syncthreads();

        const int t0 = phase ? 5 : 0;
        const int t1 = phase ? 9 : 5;
        for (int k = t0; k < t1; ++k) {
            const int ky = k / 3, kx = k % 3;
#pragma unroll
            for (int a = 0; a < 2; ++a) {
                const int p  = p0 + a * 16 + l15;
                const int h  = p >> 7, w = p & 127;
                const float o1v = OO[(((size_t)(b * 32 + k)) << 14) + p];
                const float o2v = OO[(((size_t)(b * 32 + 9 + k)) << 14) + p];
                const float ml  = OO[(((size_t)(b * 32 + 18 + k)) << 14) + p];
                const float m = 1.f / (1.f + __expf(-ml));

                const float y = (float)(h - 1 + ky) + o1v;
                const float x = (float)(w - 1 + kx) + o2v;
                const float y0f = floorf(y), x0f = floorf(x);
                const float fy = y - y0f, fx = x - x0f;
                const int y0 = (int)y0f, x0 = (int)x0f;

                const bool vy0 = (unsigned)y0 < 128u;
                const bool vy1 = (unsigned)(y0 + 1) < 128u;
                const bool vx0 = (unsigned)x0 < 128u;
                const bool vx1 = (unsigned)(x0 + 1) < 128u;

                const int y0c = min(max(y0, 0), 127);
                const int y1c = min(max(y0 + 1, 0), 127);
                const int x0c = min(max(x0, 0), 127);
                const int x1c = min(max(x0 + 1, 0), 127);

                float w00 = (1.f - fy) * (1.f - fx) * m; w00 = (vy0 && vx0) ? w00 : 0.f;
                float w01 = (1.f - fy) * fx * m;         w01 = (vy0 && vx1) ? w01 : 0.f;
                float w10 = fy * (1.f - fx) * m;         w10 = (vy1 && vx0) ? w10 : 0.f;
                float w11 = fy * fx * m;                 w11 = (vy1 && vx1) ? w11 : 0.f;

                const bf16_t* p00 = feb + ((size_t)((y0c << 7) + x0c)) * 128;
                const bf16_t* p01 = feb + ((size_t)((y0c << 7) + x1c)) * 128;
                const bf16_t* p10 = feb + ((size_t)((y1c << 7) + x0c)) * 128;
                const bf16_t* p11 = feb + ((size_t)((y1c << 7) + x1c)) * 128;

#pragma unroll
                for (int cc = 0; cc < 2; ++cc) {
                    const int c0 = cc * 32 + l4 * 8;
                    const bf16x8 v00 = *(const bf16x8*)(p00 + c0);
                    const bf16x8 v01 = *(const bf16x8*)(p01 + c0);
                    const bf16x8 v10 = *(const bf16x8*)(p10 + c0);
                    const bf16x8 v11 = *(const bf16x8*)(p11 + c0);
                    bf16x8 af;
#pragma unroll
                    for (int j = 0; j < 8; ++j) {
                        af[j] = (bf16_t)(w00 * (float)v00[j] + w01 * (float)v01[j]
                                       + w10 * (float)v10[j] + w11 * (float)v11[j]);
                    }
                    const int kcl = (k * 2 + cc) - phase * 10;
#pragma unroll
                    for (int nt = 0; nt < 4; ++nt) {
                        const bf16x8 bf = Bsv[((kcl * 4 + nt) * 4 + l4) * 16 + l15];
                        acc[a][nt] = __builtin_amdgcn_mfma_f32_16x16x32_bf16(af, bf, acc[a][nt], 0, 0, 0);
                    }
                }
            }
        }
        __syncthreads();
    }

#pragma unroll
    for (int a = 0; a < 2; ++a) {
#pragma unroll
        for (int nt = 0; nt < 4; ++nt) {
            const int o = nt * 16 + l15;
#pragma unroll
            for (int r = 0; r < 4; ++r) {
                const int p = p0 + a * 16 + l4 * 4 + r;
                out1[(((size_t)(b * 128 + 64 + o)) << 14) + p] = acc[a][nt][r];
            }
        }
    }
}

extern "C" void kernel_launch(void* const* d_in, const int* in_sizes, int n_in,
                              void* d_out, int out_size, void* d_ws, size_t ws_size,
                              hipStream_t stream) {
    const float* Fi    = (const float*)d_in[0];
    const float* Fe    = (const float*)d_in[1];
    const float* w1    = (const float*)d_in[2];
    const float* b1    = (const float*)d_in[3];
    const float* w2    = (const float*)d_in[4];
    const float* b2    = (const float*)d_in[5];
    const float* w_off = (const float*)d_in[6];
    const float* b_off = (const float*)d_in[7];
    const float* w_dcn = (const float*)d_in[8];
    const float* b_dcn = (const float*)d_in[9];

    char* wsb = (char*)d_ws;
    bf16_t* wp1   = (bf16_t*)(wsb + WP1_B);
    bf16_t* wp2   = (bf16_t*)(wsb + WP2_B);
    bf16_t* wpo   = (bf16_t*)(wsb + WPO_B);
    bf16_t* wdcnf = (bf16_t*)(wsb + WDCN_B);
    float*  bias  = (float*)(wsb + BIAS_B);
    bf16_t* Xt    = (bf16_t*)(wsb + XT_B);
    bf16_t* feat1 = (bf16_t*)(wsb + F1_B);
    bf16_t* feat2 = (bf16_t*)(wsb + F2_B);
    float*  OO    = (float*)(wsb + F1_B);    // NCHW [b][32][HW]; alias: feat1 dead after conv2

    float* out0 = (float*)d_out;                   // offset_out [8,18,128,128]
    float* out1 = out0 + (size_t)Bn * 18 * HW;     // Ff [8,128,128,128]

    prep_kernel<<<256, 256, 0, stream>>>(w1, w2, w_off, w_dcn, b1, b2, b_off, b_dcn, wsb);

    nhwc_kernel<<<dim3(256, 8), 256, 0, stream>>>(Fi, Fe, Xt);

    conv_mfma<128, 5, 64, true, false, false>
        <<<dim3(2, 32, 8), 256, 0, stream>>>(Xt, wp1, bias, feat1, nullptr, nullptr);

    conv_mfma<64, 3, 64, true, false, false>
        <<<dim3(2, 32, 8), 256, 0, stream>>>(feat1, wp2, bias + 64, feat2, nullptr, nullptr);

    conv_mfma<64, 3, 32, false, true, true>
        <<<dim3(2, 32, 8), 256, 0, stream>>>(feat2, wpo, bias + 128, nullptr, OO, out0);

    copy_fi<<<dim3(1024, 8), 256, 0, stream>>>(Fi, out1);

    dcn_mfma<<<dim3(64, 8), 512, 0, stream>>>(Xt, OO, wdcnf, bias + 160, out1);
}